// Round 4
// baseline (217.932 us; speedup 1.0000x reference)
//
#include <hip/hip_runtime.h>

// ---------------------------------------------------------------------------
// TripletLossWithHardMining  (B=4096, D=1024, fp32 in, fp32 scalar out)
//
//  K2 gemm_mask (this round's rewrite): BARRIER-FREE decoupled-wave fused
//  GEMM. Each wave owns a 64x64 quadrant of both A.N^T and A.P^T:
//   - A fragments: direct global->VGPR (MFMA A-layout == row-major 16B
//     chunks), 3-deep register pipeline (slots k%3).
//   - N/P tiles: wave-private global_load_lds(16B) staging, 2-deep LDS
//     buffers (4 waves x 2 bufs x (N+P) x 4KB = 64KB), XOR bank swizzle.
//   - Ordering: explicit s_waitcnt vmcnt(4) per iter (drains iter-k's 8 g2l
//     + 4 A loads, leaves the newest A batch in flight). No __syncthreads.
//  Unrolled by 6 (lcm of buf parity 2 and A-slot 3) so all register-array
//  indices are literals; k=30,31 peeled.
// ---------------------------------------------------------------------------

#define NB 4096
#define DIM 1024
#define EPSF 1e-6f
#define D_EPS2 (1024.0f * 1e-6f * 1e-6f)

#define BM 128           // block tile (rows and cols)
#define BK 32            // k-tile (bf16 elems) -> 64 B rows, unpadded
#define NIT (DIM / BK)   // 32 K-iterations

typedef __bf16  bf16x8 __attribute__((ext_vector_type(8)));
typedef float   f32x4  __attribute__((ext_vector_type(4)));

__device__ __forceinline__ unsigned short f2bf(float x) {
    unsigned u = __float_as_uint(x);
    u += 0x7FFFu + ((u >> 16) & 1u);   // round-to-nearest-even
    return (unsigned short)(u >> 16);
}

// async 16B/lane global->LDS; lds base wave-uniform, data lands at base+lane*16
__device__ __forceinline__ void g2l16(const unsigned short* g, unsigned short* l) {
    __builtin_amdgcn_global_load_lds(
        (const __attribute__((address_space(1))) unsigned int*)g,
        (__attribute__((address_space(3))) unsigned int*)l, 16, 0, 0);
}

// s_waitcnt imm: vmcnt in [3:0]|[15:14], expcnt=7 (ignore), lgkmcnt=15 (ignore)
#define WAIT_VM4  0x0F74   // vmcnt(4)
#define WAIT_VM0  0x0F70   // vmcnt(0)

// stats layout (NB-float slots):
// 0: base_a[i] = |a_i|^2 + 2e*sum_a + D*e^2
// 1: cn[j]     = |n_j|^2 - 2e*sum_n
// 2: cp[j]     = |p_j|^2 - 2e*sum_p
// 3: d_ap   4: d_an_row   5: hard_n bits   6: hard_p bits

__global__ __launch_bounds__(256) void row_stats_kernel(
    const float* __restrict__ a, const float* __restrict__ p,
    const float* __restrict__ n,
    unsigned short* __restrict__ abf, unsigned short* __restrict__ pbf,
    unsigned short* __restrict__ nbf, float* __restrict__ stats)
{
    const int row = blockIdx.x;
    const int t   = threadIdx.x;
    const size_t base = (size_t)row * DIM;

    float4 va = ((const float4*)(a + base))[t];
    float4 vp = ((const float4*)(p + base))[t];
    float4 vn = ((const float4*)(n + base))[t];

    float v[8] = {0,0,0,0,0,0,0,0};   // sa qa sp qp sn qn dap2 dan2
    const float fa[4] = {va.x, va.y, va.z, va.w};
    const float fp[4] = {vp.x, vp.y, vp.z, vp.w};
    const float fn[4] = {vn.x, vn.y, vn.z, vn.w};
#pragma unroll
    for (int e = 0; e < 4; e++) {
        v[0] += fa[e];           v[1] += fa[e] * fa[e];
        v[2] += fp[e];           v[3] += fp[e] * fp[e];
        v[4] += fn[e];           v[5] += fn[e] * fn[e];
        float dp = fa[e] - fp[e] + EPSF;  v[6] += dp * dp;
        float dn = fa[e] - fn[e] + EPSF;  v[7] += dn * dn;
    }

    ushort4 ba, bp, bn;
    ba.x = f2bf(fa[0]); ba.y = f2bf(fa[1]); ba.z = f2bf(fa[2]); ba.w = f2bf(fa[3]);
    bp.x = f2bf(fp[0]); bp.y = f2bf(fp[1]); bp.z = f2bf(fp[2]); bp.w = f2bf(fp[3]);
    bn.x = f2bf(fn[0]); bn.y = f2bf(fn[1]); bn.z = f2bf(fn[2]); bn.w = f2bf(fn[3]);
    ((ushort4*)(abf + base))[t] = ba;
    ((ushort4*)(pbf + base))[t] = bp;
    ((ushort4*)(nbf + base))[t] = bn;

#pragma unroll
    for (int m = 32; m >= 1; m >>= 1)
#pragma unroll
        for (int q = 0; q < 8; q++) v[q] += __shfl_xor(v[q], m);

    __shared__ float part[4][8];
    const int wave = t >> 6, lane = t & 63;
    if (lane == 0)
#pragma unroll
        for (int q = 0; q < 8; q++) part[wave][q] = v[q];
    __syncthreads();
    if (t == 0) {
        float r[8];
#pragma unroll
        for (int q = 0; q < 8; q++)
            r[q] = part[0][q] + part[1][q] + part[2][q] + part[3][q];
        stats[0 * NB + row] = r[1] + 2.0f * EPSF * r[0] + D_EPS2;  // base_a
        stats[1 * NB + row] = r[5] - 2.0f * EPSF * r[4];           // cn
        stats[2 * NB + row] = r[3] - 2.0f * EPSF * r[2];           // cp
        stats[3 * NB + row] = sqrtf(r[6]);                         // d_ap
        stats[4 * NB + row] = sqrtf(r[7]);                         // d_an_row
        ((unsigned*)stats)[5 * NB + row] = 0u;                     // hard_n
        ((unsigned*)stats)[6 * NB + row] = 0x7f800000u;            // hard_p
    }
}

// grid (32, 32): each block computes both A.N^T and A.P^T for its tile.
__global__ __launch_bounds__(256, 2) void gemm_mask_kernel(
    const unsigned short* __restrict__ Abf,
    const unsigned short* __restrict__ Nbf,
    const unsigned short* __restrict__ Pbf,
    float* __restrict__ stats)
{
    const int i0 = blockIdx.x * BM;
    const int j0 = blockIdx.y * BM;

    // [wave][buf][mat N=0/P=1][64 rows x 32 k] = 4*2*2*4KB = 64 KB
    __shared__ unsigned short sNP[4][2][2][64 * BK];

    const int t    = threadIdx.x;
    const int wave = t >> 6, lane = t & 63;
    const int wm   = wave >> 1, wn = wave & 1;
    const int quad = lane >> 4, lrow = lane & 15;

    // A-direct per-lane base: MFMA A-frag layout row=lane&15, k=quad*8
    const unsigned short* gA = Abf + (size_t)(i0 + wm * 64 + lrow) * DIM + (quad << 3);

    // g2l source bases: row = lane>>2 within 16-row chunk, XOR-swizzled chunk
    const int srow = lane >> 2;
    const int kch  = ((lane & 3) ^ ((lane >> 3) & 3)) * 8;
    const unsigned short* gN = Nbf + (size_t)(j0 + wn * 64 + srow) * DIM + kch;
    const unsigned short* gP = Pbf + (size_t)(j0 + wn * 64 + srow) * DIM + kch;

    // fragment-read swizzled chunk offset
    const int rsw = (quad ^ ((lrow >> 1) & 3)) * 8;

    bf16x8 afr[3][4];     // 3-deep A pipeline (48 VGPR)
    f32x4 accN[4][4], accP[4][4];
#pragma unroll
    for (int im = 0; im < 4; im++)
#pragma unroll
        for (int jn = 0; jn < 4; jn++) {
            accN[im][jn] = (f32x4)(0.0f);
            accP[im][jn] = (f32x4)(0.0f);
        }

#define ISSUE_G(k_, b_) do {                                                  \
    const unsigned short* _gn = gN + (size_t)(k_) * BK;                       \
    const unsigned short* _gp = gP + (size_t)(k_) * BK;                       \
    unsigned short* _ln = &sNP[wave][(b_)][0][0];                             \
    unsigned short* _lp = &sNP[wave][(b_)][1][0];                             \
    g2l16(_gn,            _ln);                                               \
    g2l16(_gn + 16 * DIM, _ln + 16 * BK);                                     \
    g2l16(_gn + 32 * DIM, _ln + 32 * BK);                                     \
    g2l16(_gn + 48 * DIM, _ln + 48 * BK);                                     \
    g2l16(_gp,            _lp);                                               \
    g2l16(_gp + 16 * DIM, _lp + 16 * BK);                                     \
    g2l16(_gp + 32 * DIM, _lp + 32 * BK);                                     \
    g2l16(_gp + 48 * DIM, _lp + 48 * BK);                                     \
} while (0)

#define ISSUE_A(k_, s_) do {                                                  \
    const unsigned short* _ga = gA + (size_t)(k_) * BK;                       \
    afr[(s_)][0] = *(const bf16x8*)(_ga);                                     \
    afr[(s_)][1] = *(const bf16x8*)(_ga + 16 * DIM);                          \
    afr[(s_)][2] = *(const bf16x8*)(_ga + 32 * DIM);                          \
    afr[(s_)][3] = *(const bf16x8*)(_ga + 48 * DIM);                          \
} while (0)

// COMPUTE(kk literal for buf/slot indices; K = k0+kk runtime col index)
#define FRAGS_MFMA(b_, s_) do {                                               \
    bf16x8 bnfr[4], bpfr[4];                                                  \
    _Pragma("unroll")                                                         \
    for (int jn = 0; jn < 4; jn++) {                                          \
        bnfr[jn] = *(const bf16x8*)(&sNP[wave][(b_)][0][(jn * 16 + lrow) * BK + rsw]); \
        bpfr[jn] = *(const bf16x8*)(&sNP[wave][(b_)][1][(jn * 16 + lrow) * BK + rsw]); \
    }                                                                         \
    _Pragma("unroll")                                                         \
    for (int im = 0; im < 4; im++)                                            \
        _Pragma("unroll")                                                     \
        for (int jn = 0; jn < 4; jn++) {                                      \
            accN[im][jn] = __builtin_amdgcn_mfma_f32_16x16x32_bf16(           \
                afr[(s_)][im], bnfr[jn], accN[im][jn], 0, 0, 0);              \
            accP[im][jn] = __builtin_amdgcn_mfma_f32_16x16x32_bf16(           \
                afr[(s_)][im], bpfr[jn], accP[im][jn], 0, 0, 0);              \
        }                                                                     \
} while (0)

#define BODY(kk_) do {                                                        \
    const int _k = k0 + (kk_);                                                \
    __builtin_amdgcn_s_waitcnt(WAIT_VM4);                                     \
    asm volatile("" ::: "memory");                                            \
    ISSUE_G(_k + 1, ((kk_) + 1) & 1);                                         \
    asm volatile("" ::: "memory");                                            \
    ISSUE_A(_k + 2, ((kk_) + 2) % 3);                                         \
    asm volatile("" ::: "memory");                                            \
    FRAGS_MFMA((kk_) & 1, (kk_) % 3);                                         \
} while (0)

    // prologue: queue = [A0(4), G0(8), A1(4)] — steady entry shape for k=0
    ISSUE_A(0, 0);
    asm volatile("" ::: "memory");
    ISSUE_G(0, 0);
    asm volatile("" ::: "memory");
    ISSUE_A(1, 1);
    asm volatile("" ::: "memory");

    for (int k0 = 0; k0 < NIT - 2; k0 += 6) {   // k = 0..29
        BODY(0); BODY(1); BODY(2); BODY(3); BODY(4); BODY(5);
    }
    {   // k = 30: slot 0, buf 0; issue G31 only (no A33)
        __builtin_amdgcn_s_waitcnt(WAIT_VM4);
        asm volatile("" ::: "memory");
        ISSUE_G(NIT - 1, 1);
        asm volatile("" ::: "memory");
        FRAGS_MFMA(0, 0);
    }
    {   // k = 31: slot 1, buf 1; drain everything
        __builtin_amdgcn_s_waitcnt(WAIT_VM0);
        asm volatile("" ::: "memory");
        FRAGS_MFMA(1, 1);
    }

#undef BODY
#undef FRAGS_MFMA
#undef ISSUE_A
#undef ISSUE_G

    // epilogue: distances + masks + row reduce + atomics (no barrier needed)
    const float* __restrict__ base_a = stats + 0 * NB;
    const float* __restrict__ cn_v   = stats + 1 * NB;
    const float* __restrict__ cp_v   = stats + 2 * NB;
    const float* __restrict__ d_ap   = stats + 3 * NB;
    const float* __restrict__ d_an   = stats + 4 * NB;
    unsigned* __restrict__ hard_n = ((unsigned*)stats) + 5 * NB;
    unsigned* __restrict__ hard_p = ((unsigned*)stats) + 6 * NB;

#pragma unroll
    for (int im = 0; im < 4; im++) {
#pragma unroll
        for (int r = 0; r < 4; r++) {
            const int gi = i0 + wm * 64 + im * 16 + quad * 4 + r;
            const float cutN = d_ap[gi];
            const float cutP = d_an[gi];
            const float bi   = base_a[gi];
            float bestN = 0.0f;
            float bestP = __uint_as_float(0x7f800000u);
#pragma unroll
            for (int jn = 0; jn < 4; jn++) {
                const int gj = j0 + wn * 64 + jn * 16 + lrow;
                const float dN = sqrtf(fmaxf(bi + cn_v[gj] - 2.0f * accN[im][jn][r], 0.0f));
                const float dP = sqrtf(fmaxf(bi + cp_v[gj] - 2.0f * accP[im][jn][r], 0.0f));
                if (dN < cutN && dN > bestN) bestN = dN;
                if (dP > cutP && dP < bestP) bestP = dP;
            }
#pragma unroll
            for (int m = 1; m < 16; m <<= 1) {
                bestN = fmaxf(bestN, __shfl_xor(bestN, m));
                bestP = fminf(bestP, __shfl_xor(bestP, m));
            }
            if (lrow == 0) {
                const unsigned bn_ = __float_as_uint(bestN);
                const unsigned bp_ = __float_as_uint(bestP);
                if (bn_ != 0u)          atomicMax(hard_n + gi, bn_);
                if (bp_ != 0x7f800000u) atomicMin(hard_p + gi, bp_);
            }
        }
    }
}

__global__ __launch_bounds__(1024) void finalize_kernel(
    const float* __restrict__ stats, float* __restrict__ out)
{
    const unsigned* hard_n = ((const unsigned*)stats) + 5 * NB;
    const unsigned* hard_p = ((const unsigned*)stats) + 6 * NB;
    const float*    d_ap   = stats + 3 * NB;
    const int t = threadIdx.x;
    const int wave = t >> 6, lane = t & 63;
    __shared__ float pn[16], pp[16];
    __shared__ float s_dan, s_dpp;

    float sn = 0.0f, sp = 0.0f;
    for (int i = t; i < NB; i += 1024) {
        sn += __uint_as_float(hard_n[i]);
        const unsigned hp = hard_p[i];
        if (hp != 0x7f800000u) sp += __uint_as_float(hp);
    }
#pragma unroll
    for (int m = 32; m >= 1; m >>= 1) {
        sn += __shfl_xor(sn, m);
        sp += __shfl_xor(sp, m);
    }
    if (lane == 0) { pn[wave] = sn; pp[wave] = sp; }
    __syncthreads();
    if (t == 0) {
        float an = 0.0f, ap = 0.0f;
#pragma unroll
        for (int w = 0; w < 16; w++) { an += pn[w]; ap += pp[w]; }
        s_dan = an / (float)NB;
        s_dpp = ap / (float)NB;
    }
    __syncthreads();
    const float dan = s_dan, dpp = s_dpp;

    float accv = 0.0f;
    for (int i = t; i < NB; i += 1024)
        accv += fmaxf(d_ap[i] - 0.5f * dpp - 0.5f * dan + 1.0f, 0.0f);
#pragma unroll
    for (int m = 32; m >= 1; m >>= 1) accv += __shfl_xor(accv, m);
    if (lane == 0) pn[wave] = accv;
    __syncthreads();
    if (t == 0) {
        float s = 0.0f;
#pragma unroll
        for (int w = 0; w < 16; w++) s += pn[w];
        out[0] = s / (float)NB;
    }
}

extern "C" void kernel_launch(void* const* d_in, const int* in_sizes, int n_in,
                              void* d_out, int out_size, void* d_ws, size_t ws_size,
                              hipStream_t stream) {
    const float* a = (const float*)d_in[0];
    const float* p = (const float*)d_in[1];
    const float* n = (const float*)d_in[2];
    float* out = (float*)d_out;

    // ws layout: abf | pbf | nbf | stats(7*NB floats)  => ~25.3 MB
    unsigned short* abf = (unsigned short*)d_ws;
    unsigned short* pbf = abf + (size_t)NB * DIM;
    unsigned short* nbf = pbf + (size_t)NB * DIM;
    float* stats = (float*)(nbf + (size_t)NB * DIM);

    row_stats_kernel<<<NB, 256, 0, stream>>>(a, p, n, abf, pbf, nbf, stats);

    dim3 grid(NB / BM, NB / BM);
    gemm_mask_kernel<<<grid, 256, 0, stream>>>(abf, nbf, pbf, stats);

    finalize_kernel<<<1, 1024, 0, stream>>>(stats, out);
}

// Round 5
// 183.398 us; speedup vs baseline: 1.1883x; 1.1883x over previous
//
#include <hip/hip_runtime.h>

// ---------------------------------------------------------------------------
// TripletLossWithHardMining  (B=4096, D=1024, fp32 in, fp32 scalar out)
//
//  K1 row_stats : wave-per-row (no LDS/barriers); combined per-row constants;
//                 d_ap, d_an_row; bf16 copies of a,p,n; init hard slots.
//  K2 gemm_mask : FUSED bf16 MFMA GEMM (A·N^T and A·P^T in one block, A tile
//                 staged once), BK=64 (16 K-iters, halved barrier count vs
//                 BK=32), global_load_lds(16B) staging + XOR chunk swizzle
//                 (slot = chunk ^ (row&7)); distance via expansion, masked
//                 row max/min reduced in-register, atomicMax/Min on uint bits.
//  K3 finalize  : d_an = mean(hard_n), d_pp = mean(hard_p, inf->0),
//                 loss = mean(relu(d_ap - 0.5*d_pp - 0.5*d_an + 1)).
//
//  R4 dead-end note: barrier-free per-wave vmcnt(4) pipeline regressed
//  (184us, MfmaUtil 15%) — doubled VMEM issue + 1-iter prefetch distance.
// ---------------------------------------------------------------------------

#define NB 4096
#define DIM 1024
#define EPSF 1e-6f
#define D_EPS2 (1024.0f * 1e-6f * 1e-6f)

#define BM 128           // block tile (rows and cols)
#define BK 64            // k-tile (bf16 elems) -> 128 B rows, unpadded

typedef __bf16  bf16x8 __attribute__((ext_vector_type(8)));
typedef float   f32x4  __attribute__((ext_vector_type(4)));

__device__ __forceinline__ unsigned short f2bf(float x) {
    unsigned u = __float_as_uint(x);
    u += 0x7FFFu + ((u >> 16) & 1u);   // round-to-nearest-even
    return (unsigned short)(u >> 16);
}

// async 16B/lane global->LDS; lds base wave-uniform, data lands at base+lane*16
__device__ __forceinline__ void g2l16(const unsigned short* g, unsigned short* l) {
    __builtin_amdgcn_global_load_lds(
        (const __attribute__((address_space(1))) unsigned int*)g,
        (__attribute__((address_space(3))) unsigned int*)l, 16, 0, 0);
}

// stats layout (NB-float slots):
// 0: base_a[i] = |a_i|^2 + 2e*sum_a + D*e^2
// 1: cn[j]     = |n_j|^2 - 2e*sum_n
// 2: cp[j]     = |p_j|^2 - 2e*sum_p
// 3: d_ap   4: d_an_row   5: hard_n bits   6: hard_p bits

// wave-per-row: 1024 blocks x 4 waves; lane handles 4 float4 chunks per matrix
__global__ __launch_bounds__(256) void row_stats_kernel(
    const float* __restrict__ a, const float* __restrict__ p,
    const float* __restrict__ n,
    unsigned short* __restrict__ abf, unsigned short* __restrict__ pbf,
    unsigned short* __restrict__ nbf, float* __restrict__ stats)
{
    const int t    = threadIdx.x;
    const int wave = t >> 6, lane = t & 63;
    const int row  = blockIdx.x * 4 + wave;
    const size_t base = (size_t)row * DIM;

    const float4* a4 = (const float4*)(a + base);
    const float4* p4 = (const float4*)(p + base);
    const float4* n4 = (const float4*)(n + base);

    float v[8] = {0,0,0,0,0,0,0,0};   // sa qa sp qp sn qn dap2 dan2
#pragma unroll
    for (int c = 0; c < 4; c++) {
        const int idx = c * 64 + lane;
        const float4 va = a4[idx];
        const float4 vp = p4[idx];
        const float4 vn = n4[idx];
        const float fa[4] = {va.x, va.y, va.z, va.w};
        const float fp[4] = {vp.x, vp.y, vp.z, vp.w};
        const float fn[4] = {vn.x, vn.y, vn.z, vn.w};
#pragma unroll
        for (int e = 0; e < 4; e++) {
            v[0] += fa[e];           v[1] += fa[e] * fa[e];
            v[2] += fp[e];           v[3] += fp[e] * fp[e];
            v[4] += fn[e];           v[5] += fn[e] * fn[e];
            float dp = fa[e] - fp[e] + EPSF;  v[6] += dp * dp;
            float dn = fa[e] - fn[e] + EPSF;  v[7] += dn * dn;
        }
        ushort4 ba, bp, bn;
        ba.x = f2bf(fa[0]); ba.y = f2bf(fa[1]); ba.z = f2bf(fa[2]); ba.w = f2bf(fa[3]);
        bp.x = f2bf(fp[0]); bp.y = f2bf(fp[1]); bp.z = f2bf(fp[2]); bp.w = f2bf(fp[3]);
        bn.x = f2bf(fn[0]); bn.y = f2bf(fn[1]); bn.z = f2bf(fn[2]); bn.w = f2bf(fn[3]);
        ((ushort4*)(abf + base))[idx] = ba;
        ((ushort4*)(pbf + base))[idx] = bp;
        ((ushort4*)(nbf + base))[idx] = bn;
    }

#pragma unroll
    for (int m = 32; m >= 1; m >>= 1)
#pragma unroll
        for (int q = 0; q < 8; q++) v[q] += __shfl_xor(v[q], m);

    if (lane == 0) {
        stats[0 * NB + row] = v[1] + 2.0f * EPSF * v[0] + D_EPS2;  // base_a
        stats[1 * NB + row] = v[5] - 2.0f * EPSF * v[4];           // cn
        stats[2 * NB + row] = v[3] - 2.0f * EPSF * v[2];           // cp
        stats[3 * NB + row] = sqrtf(v[6]);                         // d_ap
        stats[4 * NB + row] = sqrtf(v[7]);                         // d_an_row
        ((unsigned*)stats)[5 * NB + row] = 0u;                     // hard_n
        ((unsigned*)stats)[6 * NB + row] = 0x7f800000u;            // hard_p
    }
}

// grid (32, 32): each block computes both A.N^T and A.P^T for its tile.
__global__ __launch_bounds__(256, 2) void gemm_mask_kernel(
    const unsigned short* __restrict__ Abf,
    const unsigned short* __restrict__ Nbf,
    const unsigned short* __restrict__ Pbf,
    float* __restrict__ stats)
{
    const int i0 = blockIdx.x * BM;
    const int j0 = blockIdx.y * BM;

    __shared__ unsigned short sA[BM * BK];   // 16 KB each -> 48 KB total
    __shared__ unsigned short sN[BM * BK];
    __shared__ unsigned short sP[BM * BK];

    const int t    = threadIdx.x;
    const int wave = t >> 6, lane = t & 63;
    const int wm   = wave >> 1, wn = wave & 1;
    const int quad = lane >> 4, lrow = lane & 15;

    // ---- staging: wave stages rows [wave*32, wave*32+32) of each tile.
    // 8 rows per g2l instr (row = lane>>3), 4 instrs per tile per iter.
    // slot s = lane&7 of row r holds logical chunk s ^ (r&7)  (16B chunks).
    const int srow = lane >> 3;                                   // 0..7
    const int kch  = ((lane & 7) ^ srow) * 8;                     // elem offset
    const unsigned short* gA = Abf + (size_t)(i0 + wave * 32 + srow) * DIM + kch;
    const unsigned short* gN = Nbf + (size_t)(j0 + wave * 32 + srow) * DIM + kch;
    const unsigned short* gP = Pbf + (size_t)(j0 + wave * 32 + srow) * DIM + kch;
    unsigned short* lA = sA + (wave * 32) * BK;
    unsigned short* lN = sN + (wave * 32) * BK;
    unsigned short* lP = sP + (wave * 32) * BK;

    // ---- fragment read: logical chunk c = half*4+quad, physical c^(lrow&7)
    const int rsw0 = ((0 * 4 + quad) ^ (lrow & 7)) * 8;   // half 0
    const int rsw1 = ((1 * 4 + quad) ^ (lrow & 7)) * 8;   // half 1
    const unsigned short* pa  = sA + (wm * 64 + lrow) * BK;
    const unsigned short* pbn = sN + (wn * 64 + lrow) * BK;
    const unsigned short* pbp = sP + (wn * 64 + lrow) * BK;

    f32x4 accN[4][4], accP[4][4];
#pragma unroll
    for (int im = 0; im < 4; im++)
#pragma unroll
        for (int jn = 0; jn < 4; jn++) {
            accN[im][jn] = (f32x4)(0.0f);
            accP[im][jn] = (f32x4)(0.0f);
        }

    for (int kt = 0; kt < DIM; kt += BK) {
        __syncthreads();   // protect LDS from previous iteration's readers
#pragma unroll
        for (int g = 0; g < 4; g++) {
            g2l16(gA + (size_t)kt + g * 8 * DIM, lA + g * 8 * BK);
            g2l16(gN + (size_t)kt + g * 8 * DIM, lN + g * 8 * BK);
            g2l16(gP + (size_t)kt + g * 8 * DIM, lP + g * 8 * BK);
        }
        __syncthreads();   // drains vmcnt before LDS reads

#pragma unroll
        for (int half = 0; half < 2; half++) {
            const int rsw = half ? rsw1 : rsw0;
            bf16x8 afr[4], bn_fr[4], bp_fr[4];
#pragma unroll
            for (int im = 0; im < 4; im++)
                afr[im] = *(const bf16x8*)(pa + im * 16 * BK + rsw);
#pragma unroll
            for (int jn = 0; jn < 4; jn++) {
                bn_fr[jn] = *(const bf16x8*)(pbn + jn * 16 * BK + rsw);
                bp_fr[jn] = *(const bf16x8*)(pbp + jn * 16 * BK + rsw);
            }
#pragma unroll
            for (int im = 0; im < 4; im++)
#pragma unroll
                for (int jn = 0; jn < 4; jn++) {
                    accN[im][jn] = __builtin_amdgcn_mfma_f32_16x16x32_bf16(
                        afr[im], bn_fr[jn], accN[im][jn], 0, 0, 0);
                    accP[im][jn] = __builtin_amdgcn_mfma_f32_16x16x32_bf16(
                        afr[im], bp_fr[jn], accP[im][jn], 0, 0, 0);
                }
        }
    }

    // epilogue: distances + masks + row reduce + atomics
    const float* __restrict__ base_a = stats + 0 * NB;
    const float* __restrict__ cn_v   = stats + 1 * NB;
    const float* __restrict__ cp_v   = stats + 2 * NB;
    const float* __restrict__ d_ap   = stats + 3 * NB;
    const float* __restrict__ d_an   = stats + 4 * NB;
    unsigned* __restrict__ hard_n = ((unsigned*)stats) + 5 * NB;
    unsigned* __restrict__ hard_p = ((unsigned*)stats) + 6 * NB;

#pragma unroll
    for (int im = 0; im < 4; im++) {
#pragma unroll
        for (int r = 0; r < 4; r++) {
            const int gi = i0 + wm * 64 + im * 16 + quad * 4 + r;
            const float cutN = d_ap[gi];
            const float cutP = d_an[gi];
            const float bi   = base_a[gi];
            float bestN = 0.0f;
            float bestP = __uint_as_float(0x7f800000u);
#pragma unroll
            for (int jn = 0; jn < 4; jn++) {
                const int gj = j0 + wn * 64 + jn * 16 + lrow;
                const float dN = sqrtf(fmaxf(bi + cn_v[gj] - 2.0f * accN[im][jn][r], 0.0f));
                const float dP = sqrtf(fmaxf(bi + cp_v[gj] - 2.0f * accP[im][jn][r], 0.0f));
                if (dN < cutN && dN > bestN) bestN = dN;
                if (dP > cutP && dP < bestP) bestP = dP;
            }
#pragma unroll
            for (int m = 1; m < 16; m <<= 1) {
                bestN = fmaxf(bestN, __shfl_xor(bestN, m));
                bestP = fminf(bestP, __shfl_xor(bestP, m));
            }
            if (lrow == 0) {
                const unsigned bn_ = __float_as_uint(bestN);
                const unsigned bp_ = __float_as_uint(bestP);
                if (bn_ != 0u)          atomicMax(hard_n + gi, bn_);
                if (bp_ != 0x7f800000u) atomicMin(hard_p + gi, bp_);
            }
        }
    }
}

__global__ __launch_bounds__(1024) void finalize_kernel(
    const float* __restrict__ stats, float* __restrict__ out)
{
    const unsigned* hard_n = ((const unsigned*)stats) + 5 * NB;
    const unsigned* hard_p = ((const unsigned*)stats) + 6 * NB;
    const float*    d_ap   = stats + 3 * NB;
    const int t = threadIdx.x;
    const int wave = t >> 6, lane = t & 63;
    __shared__ float pn[16], pp[16];
    __shared__ float s_dan, s_dpp;

    float sn = 0.0f, sp = 0.0f;
    for (int i = t; i < NB; i += 1024) {
        sn += __uint_as_float(hard_n[i]);
        const unsigned hp = hard_p[i];
        if (hp != 0x7f800000u) sp += __uint_as_float(hp);
    }
#pragma unroll
    for (int m = 32; m >= 1; m >>= 1) {
        sn += __shfl_xor(sn, m);
        sp += __shfl_xor(sp, m);
    }
    if (lane == 0) { pn[wave] = sn; pp[wave] = sp; }
    __syncthreads();
    if (t == 0) {
        float an = 0.0f, ap = 0.0f;
#pragma unroll
        for (int w = 0; w < 16; w++) { an += pn[w]; ap += pp[w]; }
        s_dan = an / (float)NB;
        s_dpp = ap / (float)NB;
    }
    __syncthreads();
    const float dan = s_dan, dpp = s_dpp;

    float accv = 0.0f;
    for (int i = t; i < NB; i += 1024)
        accv += fmaxf(d_ap[i] - 0.5f * dpp - 0.5f * dan + 1.0f, 0.0f);
#pragma unroll
    for (int m = 32; m >= 1; m >>= 1) accv += __shfl_xor(accv, m);
    if (lane == 0) pn[wave] = accv;
    __syncthreads();
    if (t == 0) {
        float s = 0.0f;
#pragma unroll
        for (int w = 0; w < 16; w++) s += pn[w];
        out[0] = s / (float)NB;
    }
}

extern "C" void kernel_launch(void* const* d_in, const int* in_sizes, int n_in,
                              void* d_out, int out_size, void* d_ws, size_t ws_size,
                              hipStream_t stream) {
    const float* a = (const float*)d_in[0];
    const float* p = (const float*)d_in[1];
    const float* n = (const float*)d_in[2];
    float* out = (float*)d_out;

    // ws layout: abf | pbf | nbf | stats(7*NB floats)  => ~25.3 MB
    unsigned short* abf = (unsigned short*)d_ws;
    unsigned short* pbf = abf + (size_t)NB * DIM;
    unsigned short* nbf = pbf + (size_t)NB * DIM;
    float* stats = (float*)(nbf + (size_t)NB * DIM);

    row_stats_kernel<<<NB / 4, 256, 0, stream>>>(a, p, n, abf, pbf, nbf, stats);

    dim3 grid(NB / BM, NB / BM);
    gemm_mask_kernel<<<grid, 256, 0, stream>>>(abf, nbf, pbf, stats);

    finalize_kernel<<<1, 1024, 0, stream>>>(stats, out);
}